// Round 1
// baseline (766.214 us; speedup 1.0000x reference)
//
#include <hip/hip_runtime.h>
#include <cstdint>
#include <cstddef>

// ---------------- problem constants ----------------
#define BDIM  4
#define SLEN  4096
#define DIN   2048
#define MTOK  (BDIM * SLEN)   // 16384 tokens
#define NHEAD 16
#define HDIM  128
#define RANK  2
#define QRANK 8
#define NCOLS 1728            // 128 + 32 + 32 + 1024 + 256 + 256
#define NPAD  1792            // 14 * 128

// column offsets inside packed projection P[tok][NPAD]
#define OFF_AQ 0
#define OFF_AK 128
#define OFF_AV 160
#define OFF_BQ 192
#define OFF_BK 1216
#define OFF_BV 1472

// workspace layout (bytes)
#define WS_XB   ((size_t)0)                       // bf16 x      [MTOK][DIN]   67108864 B
#define WS_WT   ((size_t)67108864)                // bf16 W^T    [NPAD][DIN]    7340032 B
#define WS_COS  ((size_t)74448896)                // f32 cos     [SLEN][64]     1048576 B
#define WS_SIN  ((size_t)75497472)                // f32 sin     [SLEN][64]     1048576 B
#define WS_P    ((size_t)76546048)                // f32 P       [MTOK][NPAD] 117440512 B
// total: 193986560 B (~185 MB)

typedef __bf16 bf16x8 __attribute__((ext_vector_type(8)));
typedef float  f32x4  __attribute__((ext_vector_type(4)));

__device__ __forceinline__ unsigned short f2bf(float f) {
  unsigned int u = __float_as_uint(f);
  u += 0x7FFFu + ((u >> 16) & 1u);   // round-to-nearest-even
  return (unsigned short)(u >> 16);
}

__device__ __forceinline__ void load_lds16(const void* g, void* l) {
  __builtin_amdgcn_global_load_lds((__attribute__((address_space(1))) void*)g,
                                   (__attribute__((address_space(3))) void*)l, 16, 0, 0);
}

// ---------------- kernel 1: cast x to bf16 ----------------
__global__ __launch_bounds__(256) void k_cast_x(const float* __restrict__ x,
                                                unsigned short* __restrict__ xb) {
  const int i = (blockIdx.x * 256 + threadIdx.x) * 8;   // exact cover: MTOK*DIN/8 threads
  const float4 a = *reinterpret_cast<const float4*>(x + i);
  const float4 b = *reinterpret_cast<const float4*>(x + i + 4);
  union { unsigned short u[8]; uint4 v; } o;
  o.u[0] = f2bf(a.x); o.u[1] = f2bf(a.y); o.u[2] = f2bf(a.z); o.u[3] = f2bf(a.w);
  o.u[4] = f2bf(b.x); o.u[5] = f2bf(b.y); o.u[6] = f2bf(b.z); o.u[7] = f2bf(b.w);
  *reinterpret_cast<uint4*>(xb + i) = o.v;
}

// ---------------- kernel 2: pack W^T (bf16) + RoPE tables ----------------
__global__ __launch_bounds__(256) void k_prep_w(const float* __restrict__ Wa_q,
                                                const float* __restrict__ Wa_k,
                                                const float* __restrict__ Wa_v,
                                                const float* __restrict__ Wb_q,
                                                const float* __restrict__ Wb_k,
                                                const float* __restrict__ Wb_v,
                                                unsigned short* __restrict__ wt,
                                                float* __restrict__ cosT,
                                                float* __restrict__ sinT) {
  const int id = blockIdx.x * 256 + threadIdx.x;
  const int NW = NPAD * 256;   // one thread per 8 k-elements of one packed column
  if (id < NW) {
    const int c  = id >> 8;          // packed column 0..1791
    const int kg = (id & 255) * 8;   // k base
    union { unsigned short u[8]; uint4 v; } o;
    if (c < NCOLS) {
      const float* src; int ncol, col;
      if      (c < OFF_AK) { src = Wa_q; ncol = NHEAD * QRANK; col = c; }
      else if (c < OFF_AV) { src = Wa_k; ncol = NHEAD * RANK;  col = c - OFF_AK; }
      else if (c < OFF_BQ) { src = Wa_v; ncol = NHEAD * RANK;  col = c - OFF_AV; }
      else if (c < OFF_BK) { src = Wb_q; ncol = QRANK * HDIM;  col = c - OFF_BQ; }
      else if (c < OFF_BV) { src = Wb_k; ncol = RANK * HDIM;   col = c - OFF_BK; }
      else                 { src = Wb_v; ncol = RANK * HDIM;   col = c - OFF_BV; }
      #pragma unroll
      for (int j = 0; j < 8; ++j)
        o.u[j] = f2bf(src[(size_t)(kg + j) * ncol + col]);
    } else {
      #pragma unroll
      for (int j = 0; j < 8; ++j) o.u[j] = 0;   // zero pad columns
    }
    *reinterpret_cast<uint4*>(wt + (size_t)c * DIN + kg) = o.v;
  } else {
    const int id2 = id - NW;          // 0 .. SLEN*64-1
    const int s = id2 >> 6;
    const int j = id2 & 63;
    // inv_freq[j] = 10000^(-j/64); exact-ish via double exp, fp32 multiply like reference
    const float inv = (float)exp(-(double)j * 0.14391156831212787); // ln(1e4)/64
    const float fr  = (float)s * inv;
    cosT[id2] = cosf(fr);
    sinT[id2] = sinf(fr);
  }
}

// ---------------- kernel 3: GEMM P = x_bf16 @ W^T_bf16 (fp32 out) ----------------
// 128x128 tile, BK=32, 4 waves (2x2), each wave 64x64 = 4x4 mfma_f32_16x16x32_bf16
__global__ __launch_bounds__(256) void k_gemm(const unsigned short* __restrict__ xb,
                                              const unsigned short* __restrict__ wt,
                                              float* __restrict__ P) {
  __shared__ unsigned short sA[128 * 32];   // [row][k]  row-major, 8 KB
  __shared__ unsigned short sB[128 * 32];   // [col][k]  (W^T tile), 8 KB
  const int t    = threadIdx.x;
  const int lane = t & 63;
  const int wave = t >> 6;
  const int wm   = wave >> 1;           // 0..1 wave row
  const int wn   = wave & 1;            // 0..1 wave col
  const int tile_n = blockIdx.x;        // 0..13  (fastest -> N-tiles of same M adjacent)
  const int tile_m = blockIdx.y;        // 0..127

  const unsigned short* xbase = xb + (size_t)tile_m * 128 * DIN;
  const unsigned short* wbase = wt + (size_t)tile_n * 128 * DIN;

  const int r0 = t >> 2;          // staging row/col 0..63
  const int kg = (t & 3) * 8;     // staging k offset
  const int lh = lane & 15;
  const int kb = (lane >> 4) * 8;

  f32x4 acc[4][4] = {};

  for (int kt = 0; kt < DIN; kt += 32) {
    const unsigned short* ga = xbase + (size_t)r0 * DIN + kt + kg;
    const unsigned short* gb = wbase + (size_t)r0 * DIN + kt + kg;
    // LDS dest is linear in thread order (wave-uniform base + lane*16)
    load_lds16(ga,            &sA[t * 8]);
    load_lds16(ga + 64 * DIN, &sA[2048 + t * 8]);
    load_lds16(gb,            &sB[t * 8]);
    load_lds16(gb + 64 * DIN, &sB[2048 + t * 8]);
    __syncthreads();   // compiler drains vmcnt before s_barrier

    bf16x8 af[4], bfr[4];
    #pragma unroll
    for (int m = 0; m < 4; ++m)
      af[m] = *reinterpret_cast<const bf16x8*>(&sA[(wm * 64 + m * 16 + lh) * 32 + kb]);
    #pragma unroll
    for (int n = 0; n < 4; ++n)
      bfr[n] = *reinterpret_cast<const bf16x8*>(&sB[(wn * 64 + n * 16 + lh) * 32 + kb]);
    #pragma unroll
    for (int m = 0; m < 4; ++m) {
      #pragma unroll
      for (int n = 0; n < 4; ++n)
        acc[m][n] = __builtin_amdgcn_mfma_f32_16x16x32_bf16(af[m], bfr[n], acc[m][n], 0, 0, 0);
    }
    __syncthreads();   // all reads done before next stage overwrites LDS
  }

  // C/D layout (m89-verified): col = lane&15, row = (lane>>4)*4 + j
  const int prow0 = tile_m * 128 + wm * 64 + (lane >> 4) * 4;
  const int pcol0 = tile_n * 128 + wn * 64 + lh;
  #pragma unroll
  for (int m = 0; m < 4; ++m) {
    #pragma unroll
    for (int n = 0; n < 4; ++n) {
      #pragma unroll
      for (int j = 0; j < 4; ++j)
        P[(size_t)(prow0 + m * 16 + j) * NPAD + pcol0 + n * 16] = acc[m][n][j];
    }
  }
}

// ---------------- kernel 4: RoPE + low-rank contraction epilogue ----------------
// one wave per token; lane l owns output dims (l, l+64) = one RoPE pair
__global__ __launch_bounds__(256) void k_epi(const float* __restrict__ P,
                                             const float* __restrict__ cosT,
                                             const float* __restrict__ sinT,
                                             float* __restrict__ out) {
  const int lane = threadIdx.x & 63;
  const int wave = threadIdx.x >> 6;
  const int tkn  = blockIdx.x * 4 + wave;
  const int s    = tkn & (SLEN - 1);
  const float* row = P + (size_t)tkn * NPAD;
  const float c  = cosT[s * 64 + lane];
  const float si = sinT[s * 64 + lane];

  float y1q[QRANK], y2q[QRANK];
  #pragma unroll
  for (int r = 0; r < QRANK; ++r) {
    const float b1 = row[OFF_BQ + r * HDIM + lane];
    const float b2 = row[OFF_BQ + r * HDIM + 64 + lane];
    y1q[r] = b1 * c + b2 * si;      //  x1*cos + x2*sin
    y2q[r] = b2 * c - b1 * si;      // -x1*sin + x2*cos
  }
  float y1k[RANK], y2k[RANK];
  #pragma unroll
  for (int r = 0; r < RANK; ++r) {
    const float b1 = row[OFF_BK + r * HDIM + lane];
    const float b2 = row[OFF_BK + r * HDIM + 64 + lane];
    y1k[r] = b1 * c + b2 * si;
    y2k[r] = b2 * c - b1 * si;
  }
  float v1[RANK], v2[RANK];
  #pragma unroll
  for (int r = 0; r < RANK; ++r) {
    v1[r] = row[OFF_BV + r * HDIM + lane];
    v2[r] = row[OFF_BV + r * HDIM + 64 + lane];
  }

  const size_t qbase = (size_t)tkn * (NHEAD * HDIM);
  const size_t KOUT  = (size_t)MTOK * NHEAD * HDIM;   // 33,554,432 elements per tensor
  #pragma unroll
  for (int h = 0; h < NHEAD; ++h) {
    float q1 = 0.f, q2 = 0.f;
    #pragma unroll
    for (int r = 0; r < QRANK; ++r) {
      const float a = row[OFF_AQ + h * QRANK + r];    // wave-uniform broadcast load
      q1 += a * y1q[r]; q2 += a * y2q[r];
    }
    out[qbase + h * HDIM + lane]      = q1 * (1.f / QRANK);
    out[qbase + h * HDIM + 64 + lane] = q2 * (1.f / QRANK);

    float k1 = 0.f, k2 = 0.f, w1 = 0.f, w2 = 0.f;
    #pragma unroll
    for (int r = 0; r < RANK; ++r) {
      const float ak = row[OFF_AK + h * RANK + r];
      const float av = row[OFF_AV + h * RANK + r];
      k1 += ak * y1k[r]; k2 += ak * y2k[r];
      w1 += av * v1[r];  w2 += av * v2[r];
    }
    out[KOUT + qbase + h * HDIM + lane]          = k1 * 0.5f;
    out[KOUT + qbase + h * HDIM + 64 + lane]     = k2 * 0.5f;
    out[2 * KOUT + qbase + h * HDIM + lane]      = w1 * 0.5f;
    out[2 * KOUT + qbase + h * HDIM + 64 + lane] = w2 * 0.5f;
  }
}

// ---------------- launch ----------------
extern "C" void kernel_launch(void* const* d_in, const int* in_sizes, int n_in,
                              void* d_out, int out_size, void* d_ws, size_t ws_size,
                              hipStream_t stream) {
  const float* x    = (const float*)d_in[0];
  const float* Wa_q = (const float*)d_in[1];
  const float* Wa_k = (const float*)d_in[2];
  const float* Wa_v = (const float*)d_in[3];
  const float* Wb_q = (const float*)d_in[4];
  const float* Wb_k = (const float*)d_in[5];
  const float* Wb_v = (const float*)d_in[6];
  float* out = (float*)d_out;

  char* ws = (char*)d_ws;
  unsigned short* xb  = (unsigned short*)(ws + WS_XB);
  unsigned short* wtp = (unsigned short*)(ws + WS_WT);
  float* cosT = (float*)(ws + WS_COS);
  float* sinT = (float*)(ws + WS_SIN);
  float* P    = (float*)(ws + WS_P);

  k_cast_x<<<dim3(MTOK * DIN / (256 * 8)), dim3(256), 0, stream>>>(x, xb);
  k_prep_w<<<dim3((NPAD * 256 + SLEN * 64) / 256), dim3(256), 0, stream>>>(
      Wa_q, Wa_k, Wa_v, Wb_q, Wb_k, Wb_v, wtp, cosT, sinT);
  k_gemm<<<dim3(NPAD / 128, MTOK / 128), dim3(256), 0, stream>>>(xb, wtp, P);
  k_epi<<<dim3(MTOK / 4), dim3(256), 0, stream>>>(P, cosT, sinT, out);
}

// Round 2
// 701.727 us; speedup vs baseline: 1.0919x; 1.0919x over previous
//
#include <hip/hip_runtime.h>
#include <cstdint>
#include <cstddef>

// ---------------- problem constants ----------------
#define BDIM  4
#define SLEN  4096
#define DIN   2048
#define MTOK  (BDIM * SLEN)   // 16384 tokens
#define NHEAD 16
#define HDIM  128
#define RANK  2
#define QRANK 8
#define NCOLS 1728            // 128 + 32 + 32 + 1024 + 256 + 256
#define NPAD  1792            // 14 * 128

// column offsets inside packed projection P[tok][NPAD]
#define OFF_AQ 0
#define OFF_AK 128
#define OFF_AV 160
#define OFF_BQ 192
#define OFF_BK 1216
#define OFF_BV 1472

// workspace layout (bytes)
#define WS_XB   ((size_t)0)                       // bf16 x      [MTOK][DIN]   67108864 B
#define WS_WT   ((size_t)67108864)                // bf16 W^T    [NPAD][DIN]    7340032 B
#define WS_COS  ((size_t)74448896)                // f32 cos     [SLEN][64]     1048576 B
#define WS_SIN  ((size_t)75497472)                // f32 sin     [SLEN][64]     1048576 B
#define WS_P    ((size_t)76546048)                // f32 P       [MTOK][NPAD] 117440512 B
// total: 193986560 B (~185 MB)

typedef __bf16 bf16x8 __attribute__((ext_vector_type(8)));
typedef float  f32x4  __attribute__((ext_vector_type(4)));

__device__ __forceinline__ unsigned short f2bf(float f) {
  unsigned int u = __float_as_uint(f);
  u += 0x7FFFu + ((u >> 16) & 1u);   // round-to-nearest-even
  return (unsigned short)(u >> 16);
}

__device__ __forceinline__ void load_lds16(const void* g, void* l) {
  __builtin_amdgcn_global_load_lds((__attribute__((address_space(1))) void*)g,
                                   (__attribute__((address_space(3))) void*)l, 16, 0, 0);
}

// ---------------- kernel 1: cast x to bf16 (unchanged, validated) ----------------
__global__ __launch_bounds__(256) void k_cast_x(const float* __restrict__ x,
                                                unsigned short* __restrict__ xb) {
  const int i = (blockIdx.x * 256 + threadIdx.x) * 8;   // exact cover: MTOK*DIN/8 threads
  const float4 a = *reinterpret_cast<const float4*>(x + i);
  const float4 b = *reinterpret_cast<const float4*>(x + i + 4);
  union { unsigned short u[8]; uint4 v; } o;
  o.u[0] = f2bf(a.x); o.u[1] = f2bf(a.y); o.u[2] = f2bf(a.z); o.u[3] = f2bf(a.w);
  o.u[4] = f2bf(b.x); o.u[5] = f2bf(b.y); o.u[6] = f2bf(b.z); o.u[7] = f2bf(b.w);
  *reinterpret_cast<uint4*>(xb + i) = o.v;
}

// ---------------- kernel 2: pack W^T (bf16) + RoPE tables (unchanged) ----------------
__global__ __launch_bounds__(256) void k_prep_w(const float* __restrict__ Wa_q,
                                                const float* __restrict__ Wa_k,
                                                const float* __restrict__ Wa_v,
                                                const float* __restrict__ Wb_q,
                                                const float* __restrict__ Wb_k,
                                                const float* __restrict__ Wb_v,
                                                unsigned short* __restrict__ wt,
                                                float* __restrict__ cosT,
                                                float* __restrict__ sinT) {
  const int id = blockIdx.x * 256 + threadIdx.x;
  const int NW = NPAD * 256;   // one thread per 8 k-elements of one packed column
  if (id < NW) {
    const int c  = id >> 8;          // packed column 0..1791
    const int kg = (id & 255) * 8;   // k base
    union { unsigned short u[8]; uint4 v; } o;
    if (c < NCOLS) {
      const float* src; int ncol, col;
      if      (c < OFF_AK) { src = Wa_q; ncol = NHEAD * QRANK; col = c; }
      else if (c < OFF_AV) { src = Wa_k; ncol = NHEAD * RANK;  col = c - OFF_AK; }
      else if (c < OFF_BQ) { src = Wa_v; ncol = NHEAD * RANK;  col = c - OFF_AV; }
      else if (c < OFF_BK) { src = Wb_q; ncol = QRANK * HDIM;  col = c - OFF_BQ; }
      else if (c < OFF_BV) { src = Wb_k; ncol = RANK * HDIM;   col = c - OFF_BK; }
      else                 { src = Wb_v; ncol = RANK * HDIM;   col = c - OFF_BV; }
      #pragma unroll
      for (int j = 0; j < 8; ++j)
        o.u[j] = f2bf(src[(size_t)(kg + j) * ncol + col]);
    } else {
      #pragma unroll
      for (int j = 0; j < 8; ++j) o.u[j] = 0;   // zero pad columns
    }
    *reinterpret_cast<uint4*>(wt + (size_t)c * DIN + kg) = o.v;
  } else {
    const int id2 = id - NW;          // 0 .. SLEN*64-1
    const int s = id2 >> 6;
    const int j = id2 & 63;
    const float inv = (float)exp(-(double)j * 0.14391156831212787); // ln(1e4)/64
    const float fr  = (float)s * inv;
    cosT[id2] = cosf(fr);
    sinT[id2] = sinf(fr);
  }
}

// ---------------- kernel 3: GEMM P = x_bf16 @ W^T_bf16 (fp32 out) ----------------
// 128x128 tile, BK=64 (halved barrier count vs BK=32), 4 waves (2x2),
// LDS tiles [128][64] bf16 with XOR swizzle byte^=((row&7)<<4):
//   staging = linear LDS dest + inverse-swizzled GLOBAL source (rule #21),
//   ds_read applies the same involution -> 2-way banked (free).
__global__ __launch_bounds__(256) void k_gemm(const unsigned short* __restrict__ xb,
                                              const unsigned short* __restrict__ wt,
                                              float* __restrict__ P) {
  __shared__ unsigned short sA[128 * 64];   // 16 KB
  __shared__ unsigned short sB[128 * 64];   // 16 KB
  const int t    = threadIdx.x;
  const int lane = t & 63;
  const int wave = t >> 6;
  const int wm   = wave >> 1;           // 0..1 wave row
  const int wn   = wave & 1;            // 0..1 wave col
  const int tile_n = blockIdx.x;        // 0..13
  const int tile_m = blockIdx.y;        // 0..127

  const unsigned short* xbase = xb + (size_t)tile_m * 128 * DIN;
  const unsigned short* wbase = wt + (size_t)tile_n * 128 * DIN;

  // staging geometry: round r (0..3 each for A,B), thread t writes LDS bytes
  // [r*4096 + t*16, +16) -> row = r*32 + (t>>3), colbyte = (t&7)*16.
  // (row&7) == (t>>3)&7 for every round (32 % 8 == 0).
  const int srow    = t >> 3;                       // 0..31
  const int scolb   = (t & 7) * 16;                 // 0..112
  const int scolb_s = scolb ^ ((srow & 7) << 4);    // inverse-swizzled source col (bytes)
  const int selem   = scolb_s >> 1;                 // in bf16 elements

  const int lh = lane & 15;
  const int kbyte = (lane >> 4) * 16;               // 16B chunk within 32-elem k-substep

  f32x4 acc[4][4] = {};

  for (int kt = 0; kt < DIN; kt += 64) {
    const unsigned short* ga = xbase + (size_t)srow * DIN + kt + selem;
    const unsigned short* gb = wbase + (size_t)srow * DIN + kt + selem;
    #pragma unroll
    for (int r = 0; r < 4; ++r) {
      load_lds16(ga + (size_t)r * 32 * DIN, &sA[r * 2048 + t * 8]);
      load_lds16(gb + (size_t)r * 32 * DIN, &sB[r * 2048 + t * 8]);
    }
    __syncthreads();   // compiler drains vmcnt before s_barrier

    bf16x8 af[4][2], bfr[4][2];
    #pragma unroll
    for (int m = 0; m < 4; ++m) {
      const int row = wm * 64 + m * 16 + lh;
      const char* rb = (const char*)sA + row * 128;
      #pragma unroll
      for (int ks = 0; ks < 2; ++ks) {
        const int cb = (ks * 64 + kbyte) ^ ((row & 7) << 4);
        af[m][ks] = *reinterpret_cast<const bf16x8*>(rb + cb);
      }
    }
    #pragma unroll
    for (int n = 0; n < 4; ++n) {
      const int col = wn * 64 + n * 16 + lh;
      const char* cbp = (const char*)sB + col * 128;
      #pragma unroll
      for (int ks = 0; ks < 2; ++ks) {
        const int cb = (ks * 64 + kbyte) ^ ((col & 7) << 4);
        bfr[n][ks] = *reinterpret_cast<const bf16x8*>(cbp + cb);
      }
    }
    #pragma unroll
    for (int m = 0; m < 4; ++m) {
      #pragma unroll
      for (int n = 0; n < 4; ++n) {
        acc[m][n] = __builtin_amdgcn_mfma_f32_16x16x32_bf16(af[m][0], bfr[n][0], acc[m][n], 0, 0, 0);
        acc[m][n] = __builtin_amdgcn_mfma_f32_16x16x32_bf16(af[m][1], bfr[n][1], acc[m][n], 0, 0, 0);
      }
    }
    __syncthreads();   // all reads done before next stage overwrites LDS
  }

  // C/D layout (m89-verified): col = lane&15, row = (lane>>4)*4 + j
  const int prow0 = tile_m * 128 + wm * 64 + (lane >> 4) * 4;
  const int pcol0 = tile_n * 128 + wn * 64 + lh;
  #pragma unroll
  for (int m = 0; m < 4; ++m) {
    #pragma unroll
    for (int n = 0; n < 4; ++n) {
      #pragma unroll
      for (int j = 0; j < 4; ++j)
        P[(size_t)(prow0 + m * 16 + j) * NPAD + pcol0 + n * 16] = acc[m][n][j];
    }
  }
}

// ---------------- kernel 4: RoPE + low-rank contraction epilogue ----------------
// one wave per token; lane l owns output dims (l, l+64) = one RoPE pair.
// A-coefficients (192 f32/token) staged in LDS via coalesced loads, then
// read as wave-uniform LDS broadcasts (vs 192 global uniform loads/wave).
__global__ __launch_bounds__(256) void k_epi(const float* __restrict__ P,
                                             const float* __restrict__ cosT,
                                             const float* __restrict__ sinT,
                                             float* __restrict__ out) {
  __shared__ float sAc[4][192];   // 3 KB
  const int t    = threadIdx.x;
  const int lane = t & 63;
  const int wave = t >> 6;
  const int tkn0 = blockIdx.x * 4;

  #pragma unroll
  for (int f = t; f < 768; f += 256)
    sAc[f / 192][f % 192] = P[(size_t)(tkn0 + f / 192) * NPAD + (f % 192)];
  __syncthreads();

  const int tkn = tkn0 + wave;
  const int s   = tkn & (SLEN - 1);
  const float* row = P + (size_t)tkn * NPAD;
  const float* ac  = sAc[wave];
  const float c  = cosT[s * 64 + lane];
  const float si = sinT[s * 64 + lane];

  float y1q[QRANK], y2q[QRANK];
  #pragma unroll
  for (int r = 0; r < QRANK; ++r) {
    const float b1 = row[OFF_BQ + r * HDIM + lane];
    const float b2 = row[OFF_BQ + r * HDIM + 64 + lane];
    y1q[r] = b1 * c + b2 * si;      //  x1*cos + x2*sin
    y2q[r] = b2 * c - b1 * si;      // -x1*sin + x2*cos
  }
  float y1k[RANK], y2k[RANK];
  #pragma unroll
  for (int r = 0; r < RANK; ++r) {
    const float b1 = row[OFF_BK + r * HDIM + lane];
    const float b2 = row[OFF_BK + r * HDIM + 64 + lane];
    y1k[r] = b1 * c + b2 * si;
    y2k[r] = b2 * c - b1 * si;
  }
  float v1[RANK], v2[RANK];
  #pragma unroll
  for (int r = 0; r < RANK; ++r) {
    v1[r] = row[OFF_BV + r * HDIM + lane];
    v2[r] = row[OFF_BV + r * HDIM + 64 + lane];
  }

  const size_t qbase = (size_t)tkn * (NHEAD * HDIM);
  const size_t KOUT  = (size_t)MTOK * NHEAD * HDIM;
  #pragma unroll
  for (int h = 0; h < NHEAD; ++h) {
    float q1 = 0.f, q2 = 0.f;
    #pragma unroll
    for (int r = 0; r < QRANK; ++r) {
      const float a = ac[OFF_AQ + h * QRANK + r];   // LDS broadcast
      q1 += a * y1q[r]; q2 += a * y2q[r];
    }
    out[qbase + h * HDIM + lane]      = q1 * (1.f / QRANK);
    out[qbase + h * HDIM + 64 + lane] = q2 * (1.f / QRANK);

    float k1 = 0.f, k2 = 0.f, w1 = 0.f, w2 = 0.f;
    #pragma unroll
    for (int r = 0; r < RANK; ++r) {
      const float ak = ac[OFF_AK + h * RANK + r];
      const float av = ac[OFF_AV + h * RANK + r];
      k1 += ak * y1k[r]; k2 += ak * y2k[r];
      w1 += av * v1[r];  w2 += av * v2[r];
    }
    out[KOUT + qbase + h * HDIM + lane]          = k1 * 0.5f;
    out[KOUT + qbase + h * HDIM + 64 + lane]     = k2 * 0.5f;
    out[2 * KOUT + qbase + h * HDIM + lane]      = w1 * 0.5f;
    out[2 * KOUT + qbase + h * HDIM + 64 + lane] = w2 * 0.5f;
  }
}

// ---------------- launch ----------------
extern "C" void kernel_launch(void* const* d_in, const int* in_sizes, int n_in,
                              void* d_out, int out_size, void* d_ws, size_t ws_size,
                              hipStream_t stream) {
  const float* x    = (const float*)d_in[0];
  const float* Wa_q = (const float*)d_in[1];
  const float* Wa_k = (const float*)d_in[2];
  const float* Wa_v = (const float*)d_in[3];
  const float* Wb_q = (const float*)d_in[4];
  const float* Wb_k = (const float*)d_in[5];
  const float* Wb_v = (const float*)d_in[6];
  float* out = (float*)d_out;

  char* ws = (char*)d_ws;
  unsigned short* xb  = (unsigned short*)(ws + WS_XB);
  unsigned short* wtp = (unsigned short*)(ws + WS_WT);
  float* cosT = (float*)(ws + WS_COS);
  float* sinT = (float*)(ws + WS_SIN);
  float* P    = (float*)(ws + WS_P);

  k_cast_x<<<dim3(MTOK * DIN / (256 * 8)), dim3(256), 0, stream>>>(x, xb);
  k_prep_w<<<dim3((NPAD * 256 + SLEN * 64) / 256), dim3(256), 0, stream>>>(
      Wa_q, Wa_k, Wa_v, Wb_q, Wb_k, Wb_v, wtp, cosT, sinT);
  k_gemm<<<dim3(NPAD / 128, MTOK / 128), dim3(256), 0, stream>>>(xb, wtp, P);
  k_epi<<<dim3(MTOK / 4), dim3(256), 0, stream>>>(P, cosT, sinT, out);
}